// Round 5
// baseline (302.336 us; speedup 1.0000x reference)
//
#include <hip/hip_runtime.h>

#define DIM 128
#define SLOTS 64

typedef __attribute__((ext_vector_type(8))) short bf16x8;
typedef __attribute__((ext_vector_type(4))) float f32x4;
typedef unsigned short u16;
typedef unsigned int u32;
typedef unsigned long long u64;

__device__ __forceinline__ float bf2f(u32 u) {
    return __builtin_bit_cast(float, u << 16);
}
__device__ __forceinline__ u16 f2bf(float f) {
    u32 u = __builtin_bit_cast(u32, f);
    u = (u + 0x7FFFu + ((u >> 16) & 1u)) >> 16;   // RNE
    return (u16)u;
}
__device__ __forceinline__ u32 pack2bf(float a, float b) {
    return (u32)f2bf(a) | ((u32)f2bf(b) << 16);
}

// ---------------- fused setup: deg atomics + bucket scatter + x->bf16 + Wt build x3 ----------------

__global__ __launch_bounds__(256) void k_setup(const int* __restrict__ row, const int* __restrict__ col,
                                               const int* __restrict__ et, const float* __restrict__ ew,
                                               int E, float* __restrict__ deg, int* __restrict__ fill,
                                               u64* __restrict__ ep,
                                               const float* __restrict__ x, u16* __restrict__ xb, int nx4,
                                               const float* __restrict__ W1, const float* __restrict__ W2,
                                               const float* __restrict__ W3,
                                               u16* __restrict__ Wt1, u16* __restrict__ Wt2,
                                               u16* __restrict__ Wt3, int nEb, int nXb) {
    int b = blockIdx.x, tid = threadIdx.x;
    if (b < nEb) {
        int e = b * 256 + tid;
        if (e < E) {
            int r = row[e], c = col[e];
            atomicAdd(&deg[c], 1.0f);                 // in-degree (col counts)
            int pos = atomicAdd(&fill[r], 1);         // bucket slot for row
            if (pos < SLOTS)
                ep[(size_t)r * SLOTS + pos] =
                    ((u64)__builtin_bit_cast(u32, ew[e]) << 32) | (u32)(c | (et[e] << 16));
        }
    } else if (b < nEb + nXb) {
        int i = (b - nEb) * 256 + tid;
        if (i < nx4) {
            float4 v = ((const float4*)x)[i];
            ushort4 o;
            o.x = f2bf(v.x); o.y = f2bf(v.y); o.z = f2bf(v.z); o.w = f2bf(v.w);
            ((ushort4*)xb)[i] = o;
        }
    } else {
        int b2 = b - nEb - nXb;                    // 0..767
        const float* W = b2 < 256 ? W1 : (b2 < 512 ? W2 : W3);
        u16* Wt = b2 < 256 ? Wt1 : (b2 < 512 ? Wt2 : Wt3);
        int o = (b2 & 255) * 256 + tid;            // 0..65535
        // fragment order: o = (k>>3)*1024 + col*8 + (k&7), k = t*128 + i
        int chunk = o >> 10;
        int c = (o >> 3) & 127;
        int k = chunk * 8 + (o & 7);
        Wt[o] = f2bf(W[(k >> 7) * 16384 + (k & 127) * 128 + c]);
    }
}

__global__ void k_dis(const float* __restrict__ deg, float* __restrict__ dis, int N) {
    int i = blockIdx.x * blockDim.x + threadIdx.x;
    if (i < N) {
        float d = deg[i];
        dis[i] = d > 0.f ? rsqrtf(d) : 0.f;
    }
}

// ---------------- fused layer: bucket gather-aggregate -> LDS -> MFMA -> epilogue ----------------
// block = 1024 thr / 16 waves = 16 nodes, ONE node per wave (max memory-level parallelism).
// LDS agg tile [16][512] bf16, XOR-swizzled rows.

template <int MODE>
__global__ __launch_bounds__(1024, 8) void k_layer(const u16* __restrict__ src,
                                                   const int* __restrict__ fill,
                                                   const u64* __restrict__ ep,
                                                   const float* __restrict__ dis,
                                                   const u16* __restrict__ Wt,
                                                   const float* __restrict__ bias,
                                                   const float* __restrict__ x0,
                                                   const u16* __restrict__ z1b,
                                                   const u16* __restrict__ z2b,
                                                   float* __restrict__ outf,
                                                   u16* __restrict__ outb, int N) {
    __shared__ u16 sA[16 * 512];   // 16 KB
    int tid = threadIdx.x, wid = tid >> 6, lane = tid & 63;
    int n0 = blockIdx.x * 16;
    int n = n0 + wid;

    float2 a0 = {0.f, 0.f}, a1 = {0.f, 0.f}, a2 = {0.f, 0.f}, a3 = {0.f, 0.f};
    int cnt = 0; float dn = 0.f;
    if (n < N) {
        cnt = fill[n];
        if (cnt > SLOTS) cnt = SLOTS;
        dn = dis[n];
    }
    const u64* eb = ep + (size_t)n * SLOTS;
    const u16* xcol = src + lane * 2;

    // masked rounds of 8: 8 gathers + 8 dis reads in flight per wave
    for (int j = 0; j < cnt; j += 8) {
        u32 cc[8]; float wg[8];
        #pragma unroll
        for (int i = 0; i < 8; i++) {
            int jj = j + i;
            bool val = jj < cnt;
            u64 q = eb[val ? jj : cnt - 1];
            cc[i] = (u32)q;
            wg[i] = val ? __builtin_bit_cast(float, (u32)(q >> 32)) : 0.f;
        }
        float dc[8];
        #pragma unroll
        for (int i = 0; i < 8; i++) dc[i] = dis[cc[i] & 0xFFFF];
        u32 rv[8];
        #pragma unroll
        for (int i = 0; i < 8; i++) rv[i] = *(const u32*)(xcol + (size_t)(cc[i] & 0xFFFF) * DIM);
        #pragma unroll
        for (int i = 0; i < 8; i++) {
            float wgt = wg[i] * dc[i];
            float v0 = bf2f(rv[i] & 0xFFFFu) * wgt;
            float v1 = bf2f(rv[i] >> 16) * wgt;
            int t = (cc[i] >> 16) & 3;
            if (t == 0)      { a0.x += v0; a0.y += v1; }
            else if (t == 1) { a1.x += v0; a1.y += v1; }
            else if (t == 2) { a2.x += v0; a2.y += v1; }
            else             { a3.x += v0; a3.y += v1; }
        }
    }

    // LDS store: row = wid (node), k = t*128 + 2*lane; swizzle byte ^= (row&7)<<4
    {
        u32 X = (u32)((wid & 7) << 4);
        char* base = (char*)sA + wid * 1024;
        *(u32*)(base + ((lane * 4 + 0  ) ^ X)) = pack2bf(a0.x * dn, a0.y * dn);
        *(u32*)(base + ((lane * 4 + 256) ^ X)) = pack2bf(a1.x * dn, a1.y * dn);
        *(u32*)(base + ((lane * 4 + 512) ^ X)) = pack2bf(a2.x * dn, a2.y * dn);
        *(u32*)(base + ((lane * 4 + 768) ^ X)) = pack2bf(a3.x * dn, a3.y * dn);
    }
    __syncthreads();

    // MFMA: [16,512] @ [512,128]; waves 0..7 -> col tile wid*16
    if (wid < 8) {
        int lr = lane & 15, lk = lane >> 4;
        u32 X = (u32)((lr & 7) << 4);
        const char* ab = (const char*)sA + lr * 1024;
        const u16* bb = Wt + lk * 1024 + (wid * 16 + lr) * 8;
        f32x4 acc = {};
        #pragma unroll
        for (int ks = 0; ks < 16; ks++) {
            bf16x8 af = *(const bf16x8*)(ab + ((ks * 64 + lk * 16) ^ X));
            bf16x8 bfv = *(const bf16x8*)(bb + ks * 4096);
            acc = __builtin_amdgcn_mfma_f32_16x16x32_bf16(af, bfv, acc, 0, 0, 0);
        }

        // epilogue: col = lane&15 (+tile), row = (lane>>4)*4 + r
        int colg = wid * 16 + lr;
        float bv = bias[colg];
        #pragma unroll
        for (int r = 0; r < 4; r++) {
            int nn = n0 + lk * 4 + r;
            if (nn < N) {
                size_t idx = (size_t)nn * DIM + colg;
                float v = acc[r] + bv;
                v = v > 0.f ? v : 0.01f * v;
                if (MODE == 1)
                    outf[idx] = 0.25f * (x0[idx] + bf2f(z1b[idx]) + bf2f(z2b[idx]) + v);
                else
                    outb[idx] = f2bf(v);
            }
        }
    }
}

// ---------------- launch ----------------

extern "C" void kernel_launch(void* const* d_in, const int* in_sizes, int n_in,
                              void* d_out, int out_size, void* d_ws, size_t ws_size,
                              hipStream_t stream) {
    const float* x     = (const float*)d_in[0];
    const int*   eidx  = (const int*)d_in[1];
    const int*   etype = (const int*)d_in[2];
    const float* eattr = (const float*)d_in[3];
    const float* W1 = (const float*)d_in[4];
    const float* b1 = (const float*)d_in[5];
    const float* W2 = (const float*)d_in[6];
    const float* b2 = (const float*)d_in[7];
    const float* W3 = (const float*)d_in[8];
    const float* b3 = (const float*)d_in[9];

    const int E = in_sizes[2];
    const int N = in_sizes[0] / DIM;
    const int* row = eidx;
    const int* col = eidx + E;

    char* w = (char*)d_ws;
    size_t off = 0;
    auto alloc = [&](size_t bytes) { size_t o = off; off = (off + bytes + 255) & ~255ULL; return o; };
    size_t deg_off = alloc((size_t)N * 4);
    float* deg  = (float*)(w + deg_off);
    int*   fill = (int*)(w + alloc((size_t)N * 4));
    size_t zero_bytes = off - deg_off;
    float* dis  = (float*)(w + alloc((size_t)N * 4));
    u64*   ep   = (u64*)(w + alloc((size_t)N * SLOTS * 8));
    u16*   xb   = (u16*)(w + alloc((size_t)N * DIM * 2));
    u16*   z1b  = (u16*)(w + alloc((size_t)N * DIM * 2));
    u16*   z2b  = (u16*)(w + alloc((size_t)N * DIM * 2));
    u16*   Wt1  = (u16*)(w + alloc(65536 * 2));
    u16*   Wt2  = (u16*)(w + alloc(65536 * 2));
    u16*   Wt3  = (u16*)(w + alloc(65536 * 2));

    hipMemsetAsync(deg, 0, zero_bytes, stream);

    int nx4 = N * DIM / 4;
    int nEb = (E + 255) / 256;
    int nXb = (nx4 + 255) / 256;

    k_setup<<<nEb + nXb + 768, 256, 0, stream>>>(row, col, etype, eattr, E, deg, fill, ep,
                                                 x, xb, nx4, W1, W2, W3, Wt1, Wt2, Wt3, nEb, nXb);
    k_dis<<<(N + 255) / 256, 256, 0, stream>>>(deg, dis, N);

    int grid = (N + 15) / 16;
    k_layer<0><<<grid, 1024, 0, stream>>>(xb,  fill, ep, dis, Wt1, b1, nullptr, nullptr, nullptr, nullptr, z1b, N);
    k_layer<0><<<grid, 1024, 0, stream>>>(z1b, fill, ep, dis, Wt2, b2, nullptr, nullptr, nullptr, nullptr, z2b, N);
    k_layer<1><<<grid, 1024, 0, stream>>>(z2b, fill, ep, dis, Wt3, b3, x, z1b, z2b, (float*)d_out, nullptr, N);
}

// Round 6
// 258.732 us; speedup vs baseline: 1.1685x; 1.1685x over previous
//
#include <hip/hip_runtime.h>

#define DIM 128
#define SLOTS 64

typedef __attribute__((ext_vector_type(8))) short bf16x8;
typedef __attribute__((ext_vector_type(4))) float f32x4;
typedef unsigned short u16;
typedef unsigned int u32;
typedef unsigned long long u64;

__device__ __forceinline__ float bf2f(u32 u) {
    return __builtin_bit_cast(float, u << 16);
}
__device__ __forceinline__ u16 f2bf(float f) {
    u32 u = __builtin_bit_cast(u32, f);
    u = (u + 0x7FFFu + ((u >> 16) & 1u)) >> 16;   // RNE
    return (u16)u;
}
__device__ __forceinline__ u32 pack2bf(float a, float b) {
    return (u32)f2bf(a) | ((u32)f2bf(b) << 16);
}

// ---------------- fused setup: deg atomics + bucket scatter + x->bf16 + Wt build x3 ----------------

__global__ __launch_bounds__(256) void k_setup(const int* __restrict__ row, const int* __restrict__ col,
                                               const int* __restrict__ et, const float* __restrict__ ew,
                                               int E, float* __restrict__ deg, int* __restrict__ fill,
                                               u64* __restrict__ ep,
                                               const float* __restrict__ x, u16* __restrict__ xb, int nx4,
                                               const float* __restrict__ W1, const float* __restrict__ W2,
                                               const float* __restrict__ W3,
                                               u16* __restrict__ Wt1, u16* __restrict__ Wt2,
                                               u16* __restrict__ Wt3, int nEb, int nXb) {
    int b = blockIdx.x, tid = threadIdx.x;
    if (b < nEb) {
        int e = b * 256 + tid;
        if (e < E) {
            int r = row[e], c = col[e];
            atomicAdd(&deg[c], 1.0f);                 // in-degree (col counts)
            int pos = atomicAdd(&fill[r], 1);         // bucket slot for row
            if (pos < SLOTS)
                ep[(size_t)r * SLOTS + pos] =
                    ((u64)__builtin_bit_cast(u32, ew[e]) << 32) | (u32)(c | (et[e] << 16));
        }
    } else if (b < nEb + nXb) {
        int i = (b - nEb) * 256 + tid;
        if (i < nx4) {
            float4 v = ((const float4*)x)[i];
            ushort4 o;
            o.x = f2bf(v.x); o.y = f2bf(v.y); o.z = f2bf(v.z); o.w = f2bf(v.w);
            ((ushort4*)xb)[i] = o;
        }
    } else {
        int b2 = b - nEb - nXb;                    // 0..767
        const float* W = b2 < 256 ? W1 : (b2 < 512 ? W2 : W3);
        u16* Wt = b2 < 256 ? Wt1 : (b2 < 512 ? Wt2 : Wt3);
        int o = (b2 & 255) * 256 + tid;            // 0..65535
        // fragment order: o = (k>>3)*1024 + col*8 + (k&7), k = t*128 + i
        int chunk = o >> 10;
        int c = (o >> 3) & 127;
        int k = chunk * 8 + (o & 7);
        Wt[o] = f2bf(W[(k >> 7) * 16384 + (k & 127) * 128 + c]);
    }
}

__global__ void k_dis(const float* __restrict__ deg, float* __restrict__ dis, int N) {
    int i = blockIdx.x * blockDim.x + threadIdx.x;
    if (i < N) {
        float d = deg[i];
        dis[i] = d > 0.f ? rsqrtf(d) : 0.f;
    }
}

// ---------------- k_norm: fold full norm into bucket weights + zero-pad to multiple of 8 ----------------
// one wave per node; lane l handles slot l (coalesced 512B rows)

__global__ __launch_bounds__(256) void k_norm(const int* __restrict__ fill,
                                              const float* __restrict__ dis,
                                              u64* __restrict__ ep, int N) {
    int wid = threadIdx.x >> 6, lane = threadIdx.x & 63;
    int n = blockIdx.x * 4 + wid;
    if (n >= N) return;
    int cnt = fill[n]; if (cnt > SLOTS) cnt = SLOTS;
    int padded = (cnt + 7) & ~7;
    float dn = dis[n];
    u64* eb = ep + (size_t)n * SLOTS;
    if (lane < cnt) {
        u64 q = eb[lane];
        u32 lo = (u32)q;
        float wgt = __builtin_bit_cast(float, (u32)(q >> 32)) * dn * dis[lo & 0xFFFF];
        eb[lane] = ((u64)__builtin_bit_cast(u32, wgt) << 32) | lo;
    } else if (lane < padded) {
        eb[lane] = 0;   // zero weight, col 0, type 0
    }
}

// ---------------- fused layer: bucket gather-aggregate -> LDS -> MFMA -> epilogue ----------------
// block = 1024 thr / 16 waves = 16 nodes, one node per wave; unmasked 8-wide gather rounds.
// LDS agg tile [16][512] bf16, XOR-swizzled rows.

template <int MODE>
__global__ __launch_bounds__(1024, 4) void k_layer(const u16* __restrict__ src,
                                                   const int* __restrict__ fill,
                                                   const u64* __restrict__ ep,
                                                   const u16* __restrict__ Wt,
                                                   const float* __restrict__ bias,
                                                   const float* __restrict__ x0,
                                                   const u16* __restrict__ z1b,
                                                   const u16* __restrict__ z2b,
                                                   float* __restrict__ outf,
                                                   u16* __restrict__ outb, int N) {
    __shared__ u16 sA[16 * 512];   // 16 KB
    int tid = threadIdx.x, wid = tid >> 6, lane = tid & 63;
    int n0 = blockIdx.x * 16;
    int n = n0 + wid;

    float2 a0 = {0.f, 0.f}, a1 = {0.f, 0.f}, a2 = {0.f, 0.f}, a3 = {0.f, 0.f};
    int cnt = 0;
    if (n < N) {
        cnt = fill[n];
        if (cnt > SLOTS) cnt = SLOTS;
    }
    const u64* eb = ep + (size_t)n * SLOTS;
    const u16* xcol = src + lane * 2;

#define ACC(q, v) { float wgt_ = __builtin_bit_cast(float, (u32)((q) >> 32)); \
        float v0_ = bf2f((v) & 0xFFFFu) * wgt_, v1_ = bf2f((v) >> 16) * wgt_; \
        int t_ = (int)(((q) >> 16) & 3); \
        if (t_ == 0)      { a0.x += v0_; a0.y += v1_; } \
        else if (t_ == 1) { a1.x += v0_; a1.y += v1_; } \
        else if (t_ == 2) { a2.x += v0_; a2.y += v1_; } \
        else              { a3.x += v0_; a3.y += v1_; } }

    // buckets are zero-padded to a multiple of 8 -> no masking
    for (int j = 0; j < cnt; j += 8) {
        u64 q0 = eb[j],     q1 = eb[j + 1], q2 = eb[j + 2], q3 = eb[j + 3];
        u64 q4 = eb[j + 4], q5 = eb[j + 5], q6 = eb[j + 6], q7 = eb[j + 7];
        u32 v0 = *(const u32*)(xcol + (size_t)(q0 & 0xFFFF) * DIM);
        u32 v1 = *(const u32*)(xcol + (size_t)(q1 & 0xFFFF) * DIM);
        u32 v2 = *(const u32*)(xcol + (size_t)(q2 & 0xFFFF) * DIM);
        u32 v3 = *(const u32*)(xcol + (size_t)(q3 & 0xFFFF) * DIM);
        u32 v4 = *(const u32*)(xcol + (size_t)(q4 & 0xFFFF) * DIM);
        u32 v5 = *(const u32*)(xcol + (size_t)(q5 & 0xFFFF) * DIM);
        u32 v6 = *(const u32*)(xcol + (size_t)(q6 & 0xFFFF) * DIM);
        u32 v7 = *(const u32*)(xcol + (size_t)(q7 & 0xFFFF) * DIM);
        ACC(q0, v0); ACC(q1, v1); ACC(q2, v2); ACC(q3, v3);
        ACC(q4, v4); ACC(q5, v5); ACC(q6, v6); ACC(q7, v7);
    }
#undef ACC

    // LDS store: row = wid (node), k = t*128 + 2*lane; swizzle byte ^= (row&7)<<4
    {
        u32 X = (u32)((wid & 7) << 4);
        char* base = (char*)sA + wid * 1024;
        *(u32*)(base + ((lane * 4 + 0  ) ^ X)) = pack2bf(a0.x, a0.y);
        *(u32*)(base + ((lane * 4 + 256) ^ X)) = pack2bf(a1.x, a1.y);
        *(u32*)(base + ((lane * 4 + 512) ^ X)) = pack2bf(a2.x, a2.y);
        *(u32*)(base + ((lane * 4 + 768) ^ X)) = pack2bf(a3.x, a3.y);
    }
    __syncthreads();

    // MFMA: [16,512] @ [512,128]; waves 0..7 -> col tile wid*16
    if (wid < 8) {
        int lr = lane & 15, lk = lane >> 4;
        u32 X = (u32)((lr & 7) << 4);
        const char* ab = (const char*)sA + lr * 1024;
        const u16* bb = Wt + lk * 1024 + (wid * 16 + lr) * 8;
        f32x4 acc = {};
        #pragma unroll
        for (int ks = 0; ks < 16; ks++) {
            bf16x8 af = *(const bf16x8*)(ab + ((ks * 64 + lk * 16) ^ X));
            bf16x8 bfv = *(const bf16x8*)(bb + ks * 4096);
            acc = __builtin_amdgcn_mfma_f32_16x16x32_bf16(af, bfv, acc, 0, 0, 0);
        }

        // epilogue: col = lane&15 (+tile), row = (lane>>4)*4 + r
        int colg = wid * 16 + lr;
        float bv = bias[colg];
        #pragma unroll
        for (int r = 0; r < 4; r++) {
            int nn = n0 + lk * 4 + r;
            if (nn < N) {
                size_t idx = (size_t)nn * DIM + colg;
                float v = acc[r] + bv;
                v = v > 0.f ? v : 0.01f * v;
                if (MODE == 1)
                    outf[idx] = 0.25f * (x0[idx] + bf2f(z1b[idx]) + bf2f(z2b[idx]) + v);
                else
                    outb[idx] = f2bf(v);
            }
        }
    }
}

// ---------------- launch ----------------

extern "C" void kernel_launch(void* const* d_in, const int* in_sizes, int n_in,
                              void* d_out, int out_size, void* d_ws, size_t ws_size,
                              hipStream_t stream) {
    const float* x     = (const float*)d_in[0];
    const int*   eidx  = (const int*)d_in[1];
    const int*   etype = (const int*)d_in[2];
    const float* eattr = (const float*)d_in[3];
    const float* W1 = (const float*)d_in[4];
    const float* b1 = (const float*)d_in[5];
    const float* W2 = (const float*)d_in[6];
    const float* b2 = (const float*)d_in[7];
    const float* W3 = (const float*)d_in[8];
    const float* b3 = (const float*)d_in[9];

    const int E = in_sizes[2];
    const int N = in_sizes[0] / DIM;
    const int* row = eidx;
    const int* col = eidx + E;

    char* w = (char*)d_ws;
    size_t off = 0;
    auto alloc = [&](size_t bytes) { size_t o = off; off = (off + bytes + 255) & ~255ULL; return o; };
    size_t deg_off = alloc((size_t)N * 4);
    float* deg  = (float*)(w + deg_off);
    int*   fill = (int*)(w + alloc((size_t)N * 4));
    size_t zero_bytes = off - deg_off;
    float* dis  = (float*)(w + alloc((size_t)N * 4));
    u64*   ep   = (u64*)(w + alloc((size_t)N * SLOTS * 8));
    u16*   xb   = (u16*)(w + alloc((size_t)N * DIM * 2));
    u16*   z1b  = (u16*)(w + alloc((size_t)N * DIM * 2));
    u16*   z2b  = (u16*)(w + alloc((size_t)N * DIM * 2));
    u16*   Wt1  = (u16*)(w + alloc(65536 * 2));
    u16*   Wt2  = (u16*)(w + alloc(65536 * 2));
    u16*   Wt3  = (u16*)(w + alloc(65536 * 2));

    hipMemsetAsync(deg, 0, zero_bytes, stream);

    int nx4 = N * DIM / 4;
    int nEb = (E + 255) / 256;
    int nXb = (nx4 + 255) / 256;

    k_setup<<<nEb + nXb + 768, 256, 0, stream>>>(row, col, etype, eattr, E, deg, fill, ep,
                                                 x, xb, nx4, W1, W2, W3, Wt1, Wt2, Wt3, nEb, nXb);
    k_dis<<<(N + 255) / 256, 256, 0, stream>>>(deg, dis, N);
    k_norm<<<(N + 3) / 4, 256, 0, stream>>>(fill, dis, ep, N);

    int grid = (N + 15) / 16;
    k_layer<0><<<grid, 1024, 0, stream>>>(xb,  fill, ep, Wt1, b1, nullptr, nullptr, nullptr, nullptr, z1b, N);
    k_layer<0><<<grid, 1024, 0, stream>>>(z1b, fill, ep, Wt2, b2, nullptr, nullptr, nullptr, nullptr, z2b, N);
    k_layer<1><<<grid, 1024, 0, stream>>>(z2b, fill, ep, Wt3, b3, x, z1b, z2b, (float*)d_out, nullptr, N);
}